// Round 13
// baseline (2757.522 us; speedup 1.0000x reference)
//
#include <hip/hip_runtime.h>
#include <cstdint>
#include <cstddef>

// B=256, T=512, D=64, H=256, G=1024. Two-layer LSTM + FC.
// Pipeline (R9): one mega dispatch per d=0..18:
//   blocks 0-15: rec L0 chunk d-1 | 16-31: rec L1 chunk d-3
//   blocks 32-287: gemmA xp0(d) from x | 288-543: gemmB xp1(d-2) from h0c
// R11 (verified best, 2131us): lane-contiguous W/xp; kf0-1 LDS, kf2-5 reg,
// kf6-7 streamed. R17 (kf6->reg): slightly worse -> reverted.
// R18: fix the one elevated counter, SQ_LDS_BANK_CONFLICT (1.41M/dispatch
// ~= 1370 cyc/block/step ~= 15%): hA's 264-u16 row stride (132 words == 4
// mod 32) makes the b128 a-frag reads collide on bank groups 4(ml+q)%32.
// New hA layout [2][16][256] (512B rows) with XOR swizzle idx ^= (row&7)<<3
// (u16 units; byte-bit-4 -> 16B-aligned accesses preserved). Same mapping
// on writes and reads (G4/T2, correctness-proven in R15/R16's hAu).
#define GATES 1024
#define SEQT  512
#define TCH   32
#define NCH   16
#define XPSTEP 262144           // elements per timestep in rec-order xp
#define XPCH  8388608           // elements per chunk xp buffer (16 MB)
#define H0CCH 2097152           // elements per chunk h0c buffer (4 MB)

using u16 = unsigned short;
using bf16x8 = __attribute__((ext_vector_type(8))) short;   // 8 bf16 = 4 VGPRs
using f32x4  = __attribute__((ext_vector_type(4))) float;

__device__ __forceinline__ float bf2f(u16 u) {
    union { float f; unsigned int i; } v; v.i = ((unsigned int)u) << 16; return v.f;
}
__device__ __forceinline__ u16 f2bf(float f) {
    union { float f; unsigned int i; } v; v.f = f;
    unsigned int r = v.i + 0x7FFFu + ((v.i >> 16) & 1u);   // RNE
    return (u16)(r >> 16);
}
// overflow-safe fast activations (v_exp + v_rcp, ~1 ulp)
__device__ __forceinline__ float sigm(float x) {
    return __builtin_amdgcn_rcpf(1.f + __expf(-x));
}
__device__ __forceinline__ float tanh_f(float x) {
    return 1.f - 2.f * __builtin_amdgcn_rcpf(1.f + __expf(2.f * x));
}

// ---------------- prep ----------------
__global__ void k_conv(const float* __restrict__ src, u16* __restrict__ dst, int n) {
    int i = blockIdx.x * 256 + threadIdx.x;
    if (i < n) dst[i] = f2bf(src[i]);
}
__global__ void k_bias(const float* __restrict__ a, const float* __restrict__ b,
                       float* __restrict__ o, int n) {
    int i = blockIdx.x * 256 + threadIdx.x;
    if (i < n) o[i] = a[i] + b[i];
}
// W_hh [1024][256] -> frag-order Wf[((wave*8+kf)*8+f)*512 + lane*8 + e]
// row = (f>>1)*256 + wave*32 + (f&1)*16 + (lane&15), col = kf*32 + (lane>>4)*8 + e
__global__ void k_wshuf(const u16* __restrict__ src, u16* __restrict__ dst) {
    int idx = blockIdx.x;                 // 512 blocks = (wave*8+kf)*8+f
    int f = idx & 7, kf = (idx >> 3) & 7, wave = idx >> 6;
    int lane = threadIdx.x;               // 64 threads
    int ml = lane & 15, q = lane >> 4;
    int row = (f >> 1) * 256 + wave * 32 + (f & 1) * 16 + ml;
    int col = kf * 32 + q * 8;
    *(bf16x8*)&dst[(size_t)idx * 512 + lane * 8] =
        *(const bf16x8*)&src[(size_t)row * 256 + col];
}

// ---------------- mega: rec (32 blocks) + gemmA (256) + gemmB (256) --------
__global__ __attribute__((amdgpu_flat_work_group_size(512, 512),
                          amdgpu_waves_per_eu(2, 2))) void mega(
    const float* __restrict__ x,
    const u16* __restrict__ Wih0b, const u16* __restrict__ Whh0f,
    const u16* __restrict__ Wih1b, const u16* __restrict__ Whh1f,
    const float* __restrict__ bias0, const float* __restrict__ bias1,
    u16* __restrict__ xp0base, u16* __restrict__ xp1base,
    u16* __restrict__ h0cbase, float* __restrict__ hlast,
    u16* __restrict__ hs0, float* __restrict__ cs0,
    u16* __restrict__ hs1, float* __restrict__ cs1, int d)
{
    __shared__ __align__(16) u16 SMEM[73728];   // 147456 B, overlaid per role
    const int tid = threadIdx.x;

    if (blockIdx.x < 32) {
        // =================== rec ===================
        const int L   = blockIdx.x >> 4;
        const int blk = blockIdx.x & 15;
        const int chunk = L ? d - 3 : d - 1;
        if (chunk < 0 || chunk >= NCH) return;
        const u16* xp = (L ? xp1base : xp0base) + (size_t)(chunk & 1) * XPCH;
        const u16* Wf = L ? Whh1f : Whh0f;
        u16*  hs = L ? hs1 : hs0;
        float* cs = L ? cs1 : cs0;
        u16* h0c = h0cbase + (size_t)(chunk & 1) * H0CCH;
        const int init = (chunk == 0);

        u16* WL = SMEM;              // 131072 B (kf0-1, per-wave frag-order)
        u16* hA = SMEM + 65536;      // 16384 B: [2][16][256] XOR-swizzled

        const int wave = tid >> 6, lane = tid & 63;
        const int ml   = lane & 15, q = lane >> 4;
        const int ub   = wave * 32;
        const int bb0  = blk * 16;

        // swizzled hA u16-index: base = buf*4096 + row*256 + col,
        // idx ^= (row&7)<<3  (byte-bit-4; same map for write and b128 read)
        auto hidx = [](int buf, int row, int col) -> int {
            return (buf * 4096 + row * 256 + col) ^ ((row & 7) << 3);
        };

        // frag-order W base for this wave/lane: all accesses lane-contiguous
        const u16* wfb = Wf + (size_t)wave * 32768 + lane * 8;

        // stage W k-frags 0-1 into LDS (contiguous 1KB per wave inst)
        const int wlb = (wave * 1024 + lane) * 8;
        #pragma unroll
        for (int kf = 0; kf < 2; ++kf)
            #pragma unroll
            for (int f = 0; f < 8; ++f)
                *(bf16x8*)&WL[wlb + (kf * 8 + f) * 512] =
                    *(const bf16x8*)(wfb + (kf * 8 + f) * 512);

        // W k-frags 2-5 persistent in registers (128 regs, R11 split)
        bf16x8 wreg[4][8];
        #pragma unroll
        for (int kf = 2; kf < 6; ++kf)
            #pragma unroll
            for (int f = 0; f < 8; ++f)
                wreg[kf - 2][f] = *(const bf16x8*)(wfb + (kf * 8 + f) * 512);

        float c_[8];
        if (init) {
            for (int i = tid; i < 8192; i += 512) hA[i] = 0;
            #pragma unroll
            for (int i = 0; i < 8; ++i) c_[i] = 0.f;
        } else {
            int m = tid >> 5, j0 = (tid & 31) * 8;
            *(bf16x8*)&hA[hidx(0, m, j0)] =
                *(const bf16x8*)&hs[(size_t)(bb0 + m) * 256 + j0];
            #pragma unroll
            for (int s = 0; s < 2; ++s)
                #pragma unroll
                for (int r = 0; r < 4; ++r)
                    c_[s * 4 + r] = cs[(size_t)(bb0 + q * 4 + r) * 256 + ub + s * 16 + ml];
        }

        // xp: [t16+blk][gi][tid][8] -> per-gi contiguous 1KB per wave inst
        const u16* xpt = xp + (size_t)blk * 16384 + (size_t)tid * 8;
        const int m_st = tid >> 5;
        const int j_st = (tid & 31) * 8;

        __syncthreads();

        // prologue: xv(0)
        bf16x8 xv[4];
        #pragma unroll
        for (int gi = 0; gi < 4; ++gi)
            xv[gi] = *(const bf16x8*)(xpt + gi * 4096);

        for (int t = 0; t < TCH; ++t) {
            const int br = t & 1, bw = br ^ 1;

            f32x4 acc[4][2];
            #pragma unroll
            for (int gi = 0; gi < 4; ++gi)
                #pragma unroll
                for (int s = 0; s < 2; ++s)
                    acc[gi][s] = (f32x4)0.f;

            #pragma unroll
            for (int kf = 0; kf < 2; ++kf) {
                bf16x8 a = *(const bf16x8*)&hA[hidx(br, ml, kf * 32 + q * 8)];
                #pragma unroll
                for (int f = 0; f < 8; ++f) {
                    bf16x8 b = *(const bf16x8*)&WL[wlb + (kf * 8 + f) * 512];
                    acc[f >> 1][f & 1] = __builtin_amdgcn_mfma_f32_16x16x32_bf16(
                        a, b, acc[f >> 1][f & 1], 0, 0, 0);
                }
            }
            #pragma unroll
            for (int kf = 2; kf < 6; ++kf) {
                bf16x8 a = *(const bf16x8*)&hA[hidx(br, ml, kf * 32 + q * 8)];
                #pragma unroll
                for (int f = 0; f < 8; ++f)
                    acc[f >> 1][f & 1] = __builtin_amdgcn_mfma_f32_16x16x32_bf16(
                        a, wreg[kf - 2][f], acc[f >> 1][f & 1], 0, 0, 0);
            }
            // kf6-7 streamed from L2 (t-invariant addresses; compiler hoists)
            #pragma unroll
            for (int kf = 6; kf < 8; ++kf) {
                bf16x8 a = *(const bf16x8*)&hA[hidx(br, ml, kf * 32 + q * 8)];
                #pragma unroll
                for (int f = 0; f < 8; ++f) {
                    bf16x8 b = *(const bf16x8*)(wfb + (kf * 8 + f) * 512);
                    acc[f >> 1][f & 1] = __builtin_amdgcn_mfma_f32_16x16x32_bf16(
                        a, b, acc[f >> 1][f & 1], 0, 0, 0);
                }
            }

            // activations + cell update (xv prefetched a full step ago)
            #pragma unroll
            for (int s = 0; s < 2; ++s) {
                const int j = ub + s * 16 + ml;
                float hv[4];
                #pragma unroll
                for (int r = 0; r < 4; ++r) {
                    float ig = sigm(acc[0][s][r] + bf2f((u16)xv[0][s * 4 + r]));
                    float fg = sigm(acc[1][s][r] + bf2f((u16)xv[1][s * 4 + r]));
                    float gg = tanh_f(acc[2][s][r] + bf2f((u16)xv[2][s * 4 + r]));
                    float og = sigm(acc[3][s][r] + bf2f((u16)xv[3][s * 4 + r]));
                    float cc = fg * c_[s * 4 + r] + ig * gg;
                    c_[s * 4 + r] = cc;
                    hv[r] = og * tanh_f(cc);
                }
                unsigned p01, p23;
                asm("v_cvt_pk_bf16_f32 %0, %1, %2" : "=v"(p01) : "v"(hv[0]), "v"(hv[1]));
                asm("v_cvt_pk_bf16_f32 %0, %1, %2" : "=v"(p23) : "v"(hv[2]), "v"(hv[3]));
                hA[hidx(bw, q * 4 + 0, j)] = (u16)p01;
                hA[hidx(bw, q * 4 + 1, j)] = (u16)(p01 >> 16);
                hA[hidx(bw, q * 4 + 2, j)] = (u16)p23;
                hA[hidx(bw, q * 4 + 3, j)] = (u16)(p23 >> 16);
                if (L == 1 && chunk == NCH - 1 && t == TCH - 1) {
                    #pragma unroll
                    for (int r = 0; r < 4; ++r)
                        hlast[(size_t)(bb0 + q * 4 + r) * 256 + j] = hv[r];
                }
            }
            // reload xv for t+1 (last step reads past chunk -- mapped, unused)
            xpt += XPSTEP;
            #pragma unroll
            for (int gi = 0; gi < 4; ++gi)
                xv[gi] = *(const bf16x8*)(xpt + gi * 4096);

            // publish h(t+1): only hA ds_writes gate the barrier
            asm volatile("s_waitcnt lgkmcnt(0)\n\ts_barrier" ::: "memory");

            if (L == 0)
                *(bf16x8*)&h0c[((size_t)t * 256 + bb0 + m_st) * 256 + j_st] =
                    *(const bf16x8*)&hA[hidx(bw, m_st, j_st)];
        }

        // persist state (TCH even -> final h is in buf 0)
        #pragma unroll
        for (int s = 0; s < 2; ++s)
            #pragma unroll
            for (int r = 0; r < 4; ++r)
                cs[(size_t)(bb0 + q * 4 + r) * 256 + ub + s * 16 + ml] = c_[s * 4 + r];
        {
            int m = tid >> 5, j0 = (tid & 31) * 8;
            *(bf16x8*)&hs[(size_t)(bb0 + m) * 256 + j0] =
                *(const bf16x8*)&hA[hidx(0, m, j0)];
        }
        return;
    }

    // =================== gemm (A: xp0 from x; B: xp1 from h0c) ===================
    const int role = (blockIdx.x < 288) ? 0 : 1;
    const int bid  = blockIdx.x - (role ? 288 : 32);
    const int chunk = role ? d - 2 : d;
    if (chunk < 0 || chunk >= NCH) return;

    const int K = role ? 256 : 64;
    const u16* Wp = role ? Wih1b : Wih0b;
    const float* bias = role ? bias1 : bias0;
    u16* out = (role ? xp1base : xp0base) + (size_t)(chunk & 1) * XPCH;
    const u16* A1 = h0cbase + (size_t)(chunk & 1) * H0CCH;   // role B source

    u16 (*As)[40] = (u16 (*)[40])SMEM;            // [128][40]
    u16 (*Bs)[40] = (u16 (*)[40])(SMEM + 5120);   // [256][40]

    const int mb = bid >> 2, nb = bid & 3;
    const int n0 = nb * 256;
    const int wave = tid >> 6, lane = tid & 63;
    const int wm = wave >> 2, wn = wave & 3;      // 2 x 4 wave grid -> 128x256 tile
    const int ml = lane & 15, q = lane >> 4;
    const int tloc = mb >> 1;
    const int bbas = (mb & 1) * 128;
    const int tt = role ? tloc : chunk * TCH + tloc;

    f32x4 acc[4][4];
    #pragma unroll
    for (int mi = 0; mi < 4; ++mi)
        #pragma unroll
        for (int ni = 0; ni < 4; ++ni)
            acc[mi][ni] = (f32x4)0.f;

    const int nk = K >> 5;
    for (int kt = 0; kt < nk; ++kt) {
        __syncthreads();
        {
            int row = tid >> 2, kb = tid & 3;
            if (role) {
                *(uint4*)&As[row][kb * 8] = *(const uint4*)(
                    A1 + (size_t)tt * 65536 + (size_t)(bbas + row) * 256 + kt * 32 + kb * 8);
            } else {
                const float* xs = x + (size_t)(bbas + row) * 32768 + (size_t)tt * 64
                                    + kt * 32 + kb * 8;
                float4 fa = *(const float4*)xs;
                float4 fb = *(const float4*)(xs + 4);
                uint4 v;
                v.x = f2bf(fa.x) | ((unsigned)f2bf(fa.y) << 16);
                v.y = f2bf(fa.z) | ((unsigned)f2bf(fa.w) << 16);
                v.z = f2bf(fb.x) | ((unsigned)f2bf(fb.y) << 16);
                v.w = f2bf(fb.z) | ((unsigned)f2bf(fb.w) << 16);
                *(uint4*)&As[row][kb * 8] = v;
            }
            #pragma unroll
            for (int i = 0; i < 2; ++i) {
                int c2 = tid + i * 512, r2 = c2 >> 2, k2 = c2 & 3;
                *(uint4*)&Bs[r2][k2 * 8] = *(const uint4*)(
                    Wp + (size_t)(n0 + r2) * K + kt * 32 + k2 * 8);
            }
        }
        __syncthreads();
        bf16x8 af[4], bfr[4];
        #pragma unroll
        for (int mi = 0; mi < 4; ++mi)
            af[mi] = *(const bf16x8*)&As[wm * 64 + mi * 16 + ml][q * 8];
        #pragma unroll
        for (int ni = 0; ni < 4; ++ni)
            bfr[ni] = *(const bf16x8*)&Bs[wn * 64 + ni * 16 + ml][q * 8];
        #pragma unroll
        for (int mi = 0; mi < 4; ++mi)
            #pragma unroll
            for (int ni = 0; ni < 4; ++ni)
                acc[mi][ni] = __builtin_amdgcn_mfma_f32_16x16x32_bf16(
                    af[mi], bfr[ni], acc[mi][ni], 0, 0, 0);
    }

    // epilogue -> xp (R11 layout, VERIFIED form):
    // el = ((tloc*16+blk2)*4+gi)*512*8 ... = ((x)*512 + tid_r)*8 + s*4 + rr
    #pragma unroll
    for (int ni = 0; ni < 4; ++ni) {
        int gc = n0 + wn * 64 + ni * 16 + ml;
        int gi = gc >> 8, u = gc & 255;
        int wv = u >> 5, s = (u >> 4) & 1, mlr = u & 15;
        float bv = bias[gc];
        #pragma unroll
        for (int mi = 0; mi < 4; ++mi) {
            int rowbase = bbas + wm * 64 + mi * 16;        // multiple of 16
            int blk2 = rowbase >> 4;
            size_t el0 = ((size_t)((tloc * 16 + blk2) * 4 + gi) * 512
                          + wv * 64 + q * 16 + mlr) * 8 + s * 4;
            #pragma unroll
            for (int rr = 0; rr < 4; ++rr)
                out[el0 + rr] = f2bf(acc[mi][ni][rr] + bv);
        }
    }
}

// ---------------- FC head ----------------
__global__ void fc_k(const float* __restrict__ h, const float* __restrict__ w,
                     const float* __restrict__ b, float* __restrict__ out)
{
    int bb = blockIdx.x, lane = threadIdx.x;
    float s = 0.f;
    for (int j = lane; j < 256; j += 64) s += h[bb * 256 + j] * w[j];
    #pragma unroll
    for (int off = 32; off > 0; off >>= 1) s += __shfl_down(s, off);
    if (lane == 0) out[bb] = s + b[0];
}

extern "C" void kernel_launch(void* const* d_in, const int* in_sizes, int n_in,
                              void* d_out, int out_size, void* d_ws, size_t ws_size,
                              hipStream_t stream)
{
    const float* x    = (const float*)d_in[0];
    const float* Wih0 = (const float*)d_in[1];
    const float* Whh0 = (const float*)d_in[2];
    const float* bih0 = (const float*)d_in[3];
    const float* bhh0 = (const float*)d_in[4];
    const float* Wih1 = (const float*)d_in[5];
    const float* Whh1 = (const float*)d_in[6];
    const float* bih1 = (const float*)d_in[7];
    const float* bhh1 = (const float*)d_in[8];
    const float* fcw  = (const float*)d_in[9];
    const float* fcb  = (const float*)d_in[10];
    float* out = (float*)d_out;

    // workspace layout, total ~75.6 MB
    char* ws = (char*)d_ws;
    u16*   xp0b  = (u16*)(ws);                  // 33554432  (2 chunks)
    u16*   xp1b  = (u16*)(ws + 33554432);       // 33554432  (2 chunks)
    u16*   h0cb  = (u16*)(ws + 67108864);       //  8388608  (2 chunks)
    u16*   Wih0b = (u16*)(ws + 75497472);       //   131072
    u16*   Whh0b = (u16*)(ws + 75628544);       //   524288
    u16*   Wih1b = (u16*)(ws + 76152832);       //   524288
    u16*   Whh1b = (u16*)(ws + 76677120);       //   524288
    float* bias0 = (float*)(ws + 77201408);     //     4096
    float* bias1 = (float*)(ws + 77205504);     //     4096
    u16*   hs0   = (u16*)(ws + 77209600);       //   131072
    float* cs0   = (float*)(ws + 77340672);     //   262144
    u16*   hs1   = (u16*)(ws + 77602816);       //   131072
    float* cs1   = (float*)(ws + 77733888);     //   262144
    float* h1l   = (float*)(ws + 77996032);     //   262144
    u16*   Whh0f = (u16*)(ws + 78258176);       //   524288  frag-order W
    u16*   Whh1f = (u16*)(ws + 78782464);       //   524288

    k_conv<<<256,  256, 0, stream>>>(Wih0, Wih0b, 65536);
    k_conv<<<1024, 256, 0, stream>>>(Whh0, Whh0b, 262144);
    k_conv<<<1024, 256, 0, stream>>>(Wih1, Wih1b, 262144);
    k_conv<<<1024, 256, 0, stream>>>(Whh1, Whh1b, 262144);
    k_bias<<<4, 256, 0, stream>>>(bih0, bhh0, bias0, 1024);
    k_bias<<<4, 256, 0, stream>>>(bih1, bhh1, bias1, 1024);
    k_wshuf<<<512, 64, 0, stream>>>(Whh0b, Whh0f);
    k_wshuf<<<512, 64, 0, stream>>>(Whh1b, Whh1f);

    for (int d = 0; d <= NCH + 2; ++d)   // d = 0..18
        mega<<<544, 512, 0, stream>>>(x, Wih0b, Whh0f, Wih1b, Whh1f,
                                      bias0, bias1, xp0b, xp1b, h0cb, h1l,
                                      hs0, cs0, hs1, cs1, d);
    fc_k<<<256, 64, 0, stream>>>(h1l, fcw, fcb, out);
}

// Round 14
// 1878.672 us; speedup vs baseline: 1.4678x; 1.4678x over previous
//
#include <hip/hip_runtime.h>
#include <cstdint>
#include <cstddef>

// B=256, T=512, D=64, H=256, G=1024. Two-layer LSTM + FC.
// Pipeline (R9): one mega dispatch per d=0..18:
//   blocks 0-15: rec L0 chunk d-1 | 16-31: rec L1 chunk d-3
//   blocks 32-287: gemmA xp0(d) from x | 288-543: gemmB xp1(d-2) from h0c
// R11 (verified best, 2131us): lane-contiguous W/xp (frag-order W, rec-order
// xp); kf0-1 LDS, kf2-5 reg, kf6-7 streamed w/ 1-step lookahead.
// R17 (kf6->reg) / R18 (hA swizzle): both regressed -> reverted; conflict
// counter invariant across all three -> hA was never the conflict source.
// R19: VALU/trans diet on the activation phase (largest busy pipe ~55%):
//  (1) prescale log2e into W_hh/W_ih/bias (x1.4427 i,f,o rows; x2.8854 g)
//      -> activations use raw exp2 with free input-negate (kills 1 mul/exp).
//  (2) packed bf16 unpack (d<<16 / d&0xFFFF0000): 2 values per 2 insts.
#define GATES 1024
#define SEQT  512
#define TCH   32
#define NCH   16
#define XPSTEP 262144           // elements per timestep in rec-order xp
#define XPCH  8388608           // elements per chunk xp buffer (16 MB)
#define H0CCH 2097152           // elements per chunk h0c buffer (4 MB)

#define L2E      1.4426950408889634f
#define TWO_L2E  2.8853900817779268f

using u16 = unsigned short;
using bf16x8 = __attribute__((ext_vector_type(8))) short;   // 8 bf16 = 4 VGPRs
using f32x4  = __attribute__((ext_vector_type(4))) float;

__device__ __forceinline__ float bf2f(u16 u) {
    union { float f; unsigned int i; } v; v.i = ((unsigned int)u) << 16; return v.f;
}
__device__ __forceinline__ u16 f2bf(float f) {
    union { float f; unsigned int i; } v; v.f = f;
    unsigned int r = v.i + 0x7FFFu + ((v.i >> 16) & 1u);   // RNE
    return (u16)(r >> 16);
}
__device__ __forceinline__ float ex2(float x) {
#if __has_builtin(__builtin_amdgcn_exp2f)
    return __builtin_amdgcn_exp2f(x);
#else
    return exp2f(x);
#endif
}
// packed bf16x2 -> 2x f32 (1 inst per value)
__device__ __forceinline__ void unp(unsigned d, float& lo, float& hi) {
    union { unsigned u; float f; } a, b;
    a.u = d << 16; b.u = d & 0xFFFF0000u;
    lo = a.f; hi = b.f;
}

// ---------------- prep ----------------
__global__ void k_conv(const float* __restrict__ src, u16* __restrict__ dst, int n) {
    int i = blockIdx.x * 256 + threadIdx.x;
    if (i < n) dst[i] = f2bf(src[i]);
}
// W_ih convert with per-gate log2e prescale. rshift = log2(K): row = i>>rshift.
__global__ void k_convw(const float* __restrict__ src, u16* __restrict__ dst,
                        int n, int rshift) {
    int i = blockIdx.x * 256 + threadIdx.x;
    if (i < n) {
        int gate = (i >> rshift) >> 8;
        float s = (gate == 2) ? TWO_L2E : L2E;
        dst[i] = f2bf(src[i] * s);
    }
}
__global__ void k_bias(const float* __restrict__ a, const float* __restrict__ b,
                       float* __restrict__ o, int n) {
    int i = blockIdx.x * 256 + threadIdx.x;
    if (i < n) {
        float s = ((i >> 8) == 2) ? TWO_L2E : L2E;
        o[i] = (a[i] + b[i]) * s;
    }
}
// W_hh [1024][256] -> frag-order Wf[((wave*8+kf)*8+f)*512 + lane*8 + e],
// prescaled by gate (gate = f>>1).
// row = (f>>1)*256 + wave*32 + (f&1)*16 + (lane&15), col = kf*32 + (lane>>4)*8 + e
__global__ void k_wshuf(const u16* __restrict__ src, u16* __restrict__ dst) {
    int idx = blockIdx.x;                 // 512 blocks = (wave*8+kf)*8+f
    int f = idx & 7, kf = (idx >> 3) & 7, wave = idx >> 6;
    int lane = threadIdx.x;               // 64 threads
    int ml = lane & 15, q = lane >> 4;
    int row = (f >> 1) * 256 + wave * 32 + (f & 1) * 16 + ml;
    int col = kf * 32 + q * 8;
    float s = ((f >> 1) == 2) ? TWO_L2E : L2E;
    const u16* sp = &src[(size_t)row * 256 + col];
    u16* dp = &dst[(size_t)idx * 512 + lane * 8];
    #pragma unroll
    for (int e = 0; e < 8; ++e)
        dp[e] = f2bf(bf2f(sp[e]) * s);
}

// ---------------- mega: rec (32 blocks) + gemmA (256) + gemmB (256) --------
__global__ __attribute__((amdgpu_flat_work_group_size(512, 512),
                          amdgpu_waves_per_eu(2, 2))) void mega(
    const float* __restrict__ x,
    const u16* __restrict__ Wih0b, const u16* __restrict__ Whh0f,
    const u16* __restrict__ Wih1b, const u16* __restrict__ Whh1f,
    const float* __restrict__ bias0, const float* __restrict__ bias1,
    u16* __restrict__ xp0base, u16* __restrict__ xp1base,
    u16* __restrict__ h0cbase, float* __restrict__ hlast,
    u16* __restrict__ hs0, float* __restrict__ cs0,
    u16* __restrict__ hs1, float* __restrict__ cs1, int d)
{
    __shared__ __align__(16) u16 SMEM[73984];   // 147968 B, overlaid per role
    const int tid = threadIdx.x;

    if (blockIdx.x < 32) {
        // =================== rec ===================
        const int L   = blockIdx.x >> 4;
        const int blk = blockIdx.x & 15;
        const int chunk = L ? d - 3 : d - 1;
        if (chunk < 0 || chunk >= NCH) return;
        const u16* xp = (L ? xp1base : xp0base) + (size_t)(chunk & 1) * XPCH;
        const u16* Wf = L ? Whh1f : Whh0f;
        u16*  hs = L ? hs1 : hs0;
        float* cs = L ? cs1 : cs0;
        u16* h0c = h0cbase + (size_t)(chunk & 1) * H0CCH;
        const int init = (chunk == 0);

        u16* WL = SMEM;                                   // 131072 B
        u16 (*hAp)[264] = (u16 (*)[264])(SMEM + 65536);   // [2*16][264]

        const int wave = tid >> 6, lane = tid & 63;
        const int ml   = lane & 15, q = lane >> 4;
        const int ub   = wave * 32;
        const int bb0  = blk * 16;

        // frag-order W base for this wave/lane: all accesses lane-contiguous
        const u16* wfb = Wf + (size_t)wave * 32768 + lane * 8;

        // stage W k-frags 0-1 into LDS (contiguous 1KB per wave inst)
        const int wlb = (wave * 1024 + lane) * 8;
        #pragma unroll
        for (int kf = 0; kf < 2; ++kf)
            #pragma unroll
            for (int f = 0; f < 8; ++f)
                *(bf16x8*)&WL[wlb + (kf * 8 + f) * 512] =
                    *(const bf16x8*)(wfb + (kf * 8 + f) * 512);

        // W k-frags 2-5 persistent in registers
        bf16x8 wreg[4][8];
        #pragma unroll
        for (int kf = 2; kf < 6; ++kf)
            #pragma unroll
            for (int f = 0; f < 8; ++f)
                wreg[kf - 2][f] = *(const bf16x8*)(wfb + (kf * 8 + f) * 512);

        float c_[8];
        if (init) {
            for (int i = tid; i < 16 * 264; i += 512) ((u16*)hAp)[i] = 0;
            #pragma unroll
            for (int i = 0; i < 8; ++i) c_[i] = 0.f;
        } else {
            int m = tid >> 5, j0 = (tid & 31) * 8;
            *(bf16x8*)&hAp[m][j0] = *(const bf16x8*)&hs[(size_t)(bb0 + m) * 256 + j0];
            #pragma unroll
            for (int s = 0; s < 2; ++s)
                #pragma unroll
                for (int r = 0; r < 4; ++r)
                    c_[s * 4 + r] = cs[(size_t)(bb0 + q * 4 + r) * 256 + ub + s * 16 + ml];
        }

        // xp: [t16+blk][gi][tid][8] -> per-gi contiguous 1KB per wave inst
        const u16* xpt = xp + (size_t)blk * 16384 + (size_t)tid * 8;
        const int m_st = tid >> 5;
        const int j_st = (tid & 31) * 8;

        __syncthreads();

        // software-pipeline prologue: xv(0) and wstr prefetched before loop
        bf16x8 xv[4];
        #pragma unroll
        for (int gi = 0; gi < 4; ++gi)
            xv[gi] = *(const bf16x8*)(xpt + gi * 4096);
        bf16x8 wstr[2][8];
        #pragma unroll
        for (int kf = 0; kf < 2; ++kf)
            #pragma unroll
            for (int f = 0; f < 8; ++f)
                wstr[kf][f] = *(const bf16x8*)(wfb + ((6 + kf) * 8 + f) * 512);

        for (int t = 0; t < TCH; ++t) {
            const int br = t & 1, bw = br ^ 1;

            f32x4 acc[4][2];
            #pragma unroll
            for (int gi = 0; gi < 4; ++gi)
                #pragma unroll
                for (int s = 0; s < 2; ++s)
                    acc[gi][s] = (f32x4)0.f;

            #pragma unroll
            for (int kf = 0; kf < 2; ++kf) {
                bf16x8 a = *(const bf16x8*)&hAp[br * 16 + ml][kf * 32 + q * 8];
                #pragma unroll
                for (int f = 0; f < 8; ++f) {
                    bf16x8 b = *(const bf16x8*)&WL[wlb + (kf * 8 + f) * 512];
                    acc[f >> 1][f & 1] = __builtin_amdgcn_mfma_f32_16x16x32_bf16(
                        a, b, acc[f >> 1][f & 1], 0, 0, 0);
                }
            }
            #pragma unroll
            for (int kf = 2; kf < 6; ++kf) {
                bf16x8 a = *(const bf16x8*)&hAp[br * 16 + ml][kf * 32 + q * 8];
                #pragma unroll
                for (int f = 0; f < 8; ++f)
                    acc[f >> 1][f & 1] = __builtin_amdgcn_mfma_f32_16x16x32_bf16(
                        a, wreg[kf - 2][f], acc[f >> 1][f & 1], 0, 0, 0);
            }
            // kf6-7: wstr was prefetched a full step ago -> no VMEM stall here
            #pragma unroll
            for (int kf = 6; kf < 8; ++kf) {
                bf16x8 a = *(const bf16x8*)&hAp[br * 16 + ml][kf * 32 + q * 8];
                #pragma unroll
                for (int f = 0; f < 8; ++f)
                    acc[f >> 1][f & 1] = __builtin_amdgcn_mfma_f32_16x16x32_bf16(
                        a, wstr[kf - 6][f], acc[f >> 1][f & 1], 0, 0, 0);
            }
            // reload wstr for t+1 (WAR orders issue here; drains under step)
            #pragma unroll
            for (int kf = 0; kf < 2; ++kf)
                #pragma unroll
                for (int f = 0; f < 8; ++f)
                    wstr[kf][f] = *(const bf16x8*)(wfb + ((6 + kf) * 8 + f) * 512);

            // activations + cell update. Pre-activations arrive prescaled by
            // log2e (2log2e for g) via W/bias -> raw exp2, negate is a free
            // input modifier. Packed bf16 unpack: 1 inst/value.
            #pragma unroll
            for (int s = 0; s < 2; ++s) {
                const int j = ub + s * 16 + ml;
                float xf[4][4];
                #pragma unroll
                for (int gi = 0; gi < 4; ++gi) {
                    const unsigned* xd = (const unsigned*)&xv[gi];
                    unp(xd[s * 2],     xf[gi][0], xf[gi][1]);
                    unp(xd[s * 2 + 1], xf[gi][2], xf[gi][3]);
                }
                float hv[4];
                #pragma unroll
                for (int r = 0; r < 4; ++r) {
                    float ig = __builtin_amdgcn_rcpf(1.f + ex2(-(acc[0][s][r] + xf[0][r])));
                    float fg = __builtin_amdgcn_rcpf(1.f + ex2(-(acc[1][s][r] + xf[1][r])));
                    float gg = 1.f - 2.f * __builtin_amdgcn_rcpf(1.f + ex2(acc[2][s][r] + xf[2][r]));
                    float og = __builtin_amdgcn_rcpf(1.f + ex2(-(acc[3][s][r] + xf[3][r])));
                    float cc = fg * c_[s * 4 + r] + ig * gg;
                    c_[s * 4 + r] = cc;
                    hv[r] = og * (1.f - 2.f * __builtin_amdgcn_rcpf(1.f + ex2(cc * TWO_L2E)));
                }
                unsigned p01, p23;
                asm("v_cvt_pk_bf16_f32 %0, %1, %2" : "=v"(p01) : "v"(hv[0]), "v"(hv[1]));
                asm("v_cvt_pk_bf16_f32 %0, %1, %2" : "=v"(p23) : "v"(hv[2]), "v"(hv[3]));
                hAp[bw * 16 + q * 4 + 0][j] = (u16)p01;
                hAp[bw * 16 + q * 4 + 1][j] = (u16)(p01 >> 16);
                hAp[bw * 16 + q * 4 + 2][j] = (u16)p23;
                hAp[bw * 16 + q * 4 + 3][j] = (u16)(p23 >> 16);
                if (L == 1 && chunk == NCH - 1 && t == TCH - 1) {
                    #pragma unroll
                    for (int r = 0; r < 4; ++r)
                        hlast[(size_t)(bb0 + q * 4 + r) * 256 + j] = hv[r];
                }
            }
            // reload xv for t+1 (last step reads past chunk -- mapped, unused)
            xpt += XPSTEP;
            #pragma unroll
            for (int gi = 0; gi < 4; ++gi)
                xv[gi] = *(const bf16x8*)(xpt + gi * 4096);

            // publish h(t+1): only hA ds_writes gate the barrier
            asm volatile("s_waitcnt lgkmcnt(0)\n\ts_barrier" ::: "memory");

            if (L == 0)
                *(bf16x8*)&h0c[((size_t)t * 256 + bb0 + m_st) * 256 + j_st] =
                    *(const bf16x8*)&hAp[bw * 16 + m_st][j_st];
        }

        // persist state (TCH even -> final h is in buf 0)
        #pragma unroll
        for (int s = 0; s < 2; ++s)
            #pragma unroll
            for (int r = 0; r < 4; ++r)
                cs[(size_t)(bb0 + q * 4 + r) * 256 + ub + s * 16 + ml] = c_[s * 4 + r];
        {
            int m = tid >> 5, j0 = (tid & 31) * 8;
            *(bf16x8*)&hs[(size_t)(bb0 + m) * 256 + j0] = *(const bf16x8*)&hAp[m][j0];
        }
        return;
    }

    // =================== gemm (A: xp0 from x; B: xp1 from h0c) ===================
    const int role = (blockIdx.x < 288) ? 0 : 1;
    const int bid  = blockIdx.x - (role ? 288 : 32);
    const int chunk = role ? d - 2 : d;
    if (chunk < 0 || chunk >= NCH) return;

    const int K = role ? 256 : 64;
    const u16* Wp = role ? Wih1b : Wih0b;
    const float* bias = role ? bias1 : bias0;
    u16* out = (role ? xp1base : xp0base) + (size_t)(chunk & 1) * XPCH;
    const u16* A1 = h0cbase + (size_t)(chunk & 1) * H0CCH;   // role B source

    u16 (*As)[40] = (u16 (*)[40])SMEM;            // [128][40]
    u16 (*Bs)[40] = (u16 (*)[40])(SMEM + 5120);   // [256][40]

    const int mb = bid >> 2, nb = bid & 3;
    const int n0 = nb * 256;
    const int wave = tid >> 6, lane = tid & 63;
    const int wm = wave >> 2, wn = wave & 3;      // 2 x 4 wave grid -> 128x256 tile
    const int ml = lane & 15, q = lane >> 4;
    const int tloc = mb >> 1;
    const int bbas = (mb & 1) * 128;
    const int tt = role ? tloc : chunk * TCH + tloc;

    f32x4 acc[4][4];
    #pragma unroll
    for (int mi = 0; mi < 4; ++mi)
        #pragma unroll
        for (int ni = 0; ni < 4; ++ni)
            acc[mi][ni] = (f32x4)0.f;

    const int nk = K >> 5;
    for (int kt = 0; kt < nk; ++kt) {
        __syncthreads();
        {
            int row = tid >> 2, kb = tid & 3;
            if (role) {
                *(uint4*)&As[row][kb * 8] = *(const uint4*)(
                    A1 + (size_t)tt * 65536 + (size_t)(bbas + row) * 256 + kt * 32 + kb * 8);
            } else {
                const float* xs = x + (size_t)(bbas + row) * 32768 + (size_t)tt * 64
                                    + kt * 32 + kb * 8;
                float4 fa = *(const float4*)xs;
                float4 fb = *(const float4*)(xs + 4);
                uint4 v;
                v.x = f2bf(fa.x) | ((unsigned)f2bf(fa.y) << 16);
                v.y = f2bf(fa.z) | ((unsigned)f2bf(fa.w) << 16);
                v.z = f2bf(fb.x) | ((unsigned)f2bf(fb.y) << 16);
                v.w = f2bf(fb.z) | ((unsigned)f2bf(fb.w) << 16);
                *(uint4*)&As[row][kb * 8] = v;
            }
            #pragma unroll
            for (int i = 0; i < 2; ++i) {
                int c2 = tid + i * 512, r2 = c2 >> 2, k2 = c2 & 3;
                *(uint4*)&Bs[r2][k2 * 8] = *(const uint4*)(
                    Wp + (size_t)(n0 + r2) * K + kt * 32 + k2 * 8);
            }
        }
        __syncthreads();
        bf16x8 af[4], bfr[4];
        #pragma unroll
        for (int mi = 0; mi < 4; ++mi)
            af[mi] = *(const bf16x8*)&As[wm * 64 + mi * 16 + ml][q * 8];
        #pragma unroll
        for (int ni = 0; ni < 4; ++ni)
            bfr[ni] = *(const bf16x8*)&Bs[wn * 64 + ni * 16 + ml][q * 8];
        #pragma unroll
        for (int mi = 0; mi < 4; ++mi)
            #pragma unroll
            for (int ni = 0; ni < 4; ++ni)
                acc[mi][ni] = __builtin_amdgcn_mfma_f32_16x16x32_bf16(
                    af[mi], bfr[ni], acc[mi][ni], 0, 0, 0);
    }

    // epilogue -> xp (R11 layout, VERIFIED form):
    // el = ((tloc*16+blk2)*4+gi)*512*8 ... = ((x)*512 + tid_r)*8 + s*4 + rr
    #pragma unroll
    for (int ni = 0; ni < 4; ++ni) {
        int gc = n0 + wn * 64 + ni * 16 + ml;
        int gi = gc >> 8, u = gc & 255;
        int wv = u >> 5, s = (u >> 4) & 1, mlr = u & 15;
        float bv = bias[gc];
        #pragma unroll
        for (int mi = 0; mi < 4; ++mi) {
            int rowbase = bbas + wm * 64 + mi * 16;        // multiple of 16
            int blk2 = rowbase >> 4;
            size_t el0 = ((size_t)((tloc * 16 + blk2) * 4 + gi) * 512
                          + wv * 64 + q * 16 + mlr) * 8 + s * 4;
            #pragma unroll
            for (int rr = 0; rr < 4; ++rr)
                out[el0 + rr] = f2bf(acc[mi][ni][rr] + bv);
        }
    }
}

// ---------------- FC head ----------------
__global__ void fc_k(const float* __restrict__ h, const float* __restrict__ w,
                     const float* __restrict__ b, float* __restrict__ out)
{
    int bb = blockIdx.x, lane = threadIdx.x;
    float s = 0.f;
    for (int j = lane; j < 256; j += 64) s += h[bb * 256 + j] * w[j];
    #pragma unroll
    for (int off = 32; off > 0; off >>= 1) s += __shfl_down(s, off);
    if (lane == 0) out[bb] = s + b[0];
}

extern "C" void kernel_launch(void* const* d_in, const int* in_sizes, int n_in,
                              void* d_out, int out_size, void* d_ws, size_t ws_size,
                              hipStream_t stream)
{
    const float* x    = (const float*)d_in[0];
    const float* Wih0 = (const float*)d_in[1];
    const float* Whh0 = (const float*)d_in[2];
    const float* bih0 = (const float*)d_in[3];
    const float* bhh0 = (const float*)d_in[4];
    const float* Wih1 = (const float*)d_in[5];
    const float* Whh1 = (const float*)d_in[6];
    const float* bih1 = (const float*)d_in[7];
    const float* bhh1 = (const float*)d_in[8];
    const float* fcw  = (const float*)d_in[9];
    const float* fcb  = (const float*)d_in[10];
    float* out = (float*)d_out;

    // workspace layout, total ~75.6 MB
    char* ws = (char*)d_ws;
    u16*   xp0b  = (u16*)(ws);                  // 33554432  (2 chunks)
    u16*   xp1b  = (u16*)(ws + 33554432);       // 33554432  (2 chunks)
    u16*   h0cb  = (u16*)(ws + 67108864);       //  8388608  (2 chunks)
    u16*   Wih0b = (u16*)(ws + 75497472);       //   131072
    u16*   Whh0b = (u16*)(ws + 75628544);       //   524288
    u16*   Wih1b = (u16*)(ws + 76152832);       //   524288
    u16*   Whh1b = (u16*)(ws + 76677120);       //   524288
    float* bias0 = (float*)(ws + 77201408);     //     4096
    float* bias1 = (float*)(ws + 77205504);     //     4096
    u16*   hs0   = (u16*)(ws + 77209600);       //   131072
    float* cs0   = (float*)(ws + 77340672);     //   262144
    u16*   hs1   = (u16*)(ws + 77602816);       //   131072
    float* cs1   = (float*)(ws + 77733888);     //   262144
    float* h1l   = (float*)(ws + 77996032);     //   262144
    u16*   Whh0f = (u16*)(ws + 78258176);       //   524288  frag-order W (scaled)
    u16*   Whh1f = (u16*)(ws + 78782464);       //   524288

    k_convw<<<256,  256, 0, stream>>>(Wih0, Wih0b, 65536, 6);    // K=64
    k_conv<<<1024, 256, 0, stream>>>(Whh0, Whh0b, 262144);
    k_convw<<<1024, 256, 0, stream>>>(Wih1, Wih1b, 262144, 8);   // K=256
    k_conv<<<1024, 256, 0, stream>>>(Whh1, Whh1b, 262144);
    k_bias<<<4, 256, 0, stream>>>(bih0, bhh0, bias0, 1024);
    k_bias<<<4, 256, 0, stream>>>(bih1, bhh1, bias1, 1024);
    k_wshuf<<<512, 64, 0, stream>>>(Whh0b, Whh0f);
    k_wshuf<<<512, 64, 0, stream>>>(Whh1b, Whh1f);

    for (int d = 0; d <= NCH + 2; ++d)   // d = 0..18
        mega<<<544, 512, 0, stream>>>(x, Wih0b, Whh0f, Wih1b, Whh1f,
                                      bias0, bias1, xp0b, xp1b, h0cb, h1l,
                                      hs0, cs0, hs1, cs1, d);
    fc_k<<<256, 64, 0, stream>>>(h1l, fcw, fcb, out);
}

// Round 15
// 1652.536 us; speedup vs baseline: 1.6687x; 1.1368x over previous
//
#include <hip/hip_runtime.h>
#include <cstdint>
#include <cstddef>

// B=256, T=512, D=64, H=256, G=1024. Two-layer LSTM + FC.
// Pipeline (R9): one mega dispatch per d=0..18:
//   blocks 0-15: rec L0 chunk d-1 | 16-31: rec L1 chunk d-3
//   blocks 32-287: gemmA xp0(d) from x | 288-543: gemmB xp1(d-2) from h0c
// R11: lane-contiguous W/xp; kf0-1 LDS, kf2-5 reg, kf6-7 streamed.
// R19 (verified 1879us): log2e prescaled into W/bias -> raw exp2 activations;
// packed bf16 unpack. VALU-diet confirmed: activation chain is the lever.
// R20: two more chain cuts:
//  (1) xp folded into MFMA acc init (C-in accumulates) -> kills 32 post-adds.
//  (2) c kept in 2log2e domain (gg' = 2L2E - 4L2E*u, same fma) -> kills the
//      8 cc*2L2E muls on the tanh chain; rescale only at chunk load/persist.
#define GATES 1024
#define SEQT  512
#define TCH   32
#define NCH   16
#define XPSTEP 262144           // elements per timestep in rec-order xp
#define XPCH  8388608           // elements per chunk xp buffer (16 MB)
#define H0CCH 2097152           // elements per chunk h0c buffer (4 MB)

#define L2E      1.4426950408889634f
#define TWO_L2E  2.8853900817779268f
#define FOUR_L2E 5.7707801635558536f
#define INV_TWO_L2E 0.34657359027997264f

using u16 = unsigned short;
using bf16x8 = __attribute__((ext_vector_type(8))) short;   // 8 bf16 = 4 VGPRs
using f32x4  = __attribute__((ext_vector_type(4))) float;

__device__ __forceinline__ float bf2f(u16 u) {
    union { float f; unsigned int i; } v; v.i = ((unsigned int)u) << 16; return v.f;
}
__device__ __forceinline__ u16 f2bf(float f) {
    union { float f; unsigned int i; } v; v.f = f;
    unsigned int r = v.i + 0x7FFFu + ((v.i >> 16) & 1u);   // RNE
    return (u16)(r >> 16);
}
__device__ __forceinline__ float ex2(float x) {
#if __has_builtin(__builtin_amdgcn_exp2f)
    return __builtin_amdgcn_exp2f(x);
#else
    return exp2f(x);
#endif
}
// packed bf16x2 -> 2x f32 (1 inst per value)
__device__ __forceinline__ void unp(unsigned d, float& lo, float& hi) {
    union { unsigned u; float f; } a, b;
    a.u = d << 16; b.u = d & 0xFFFF0000u;
    lo = a.f; hi = b.f;
}

// ---------------- prep ----------------
__global__ void k_conv(const float* __restrict__ src, u16* __restrict__ dst, int n) {
    int i = blockIdx.x * 256 + threadIdx.x;
    if (i < n) dst[i] = f2bf(src[i]);
}
// W_ih convert with per-gate log2e prescale. rshift = log2(K): row = i>>rshift.
__global__ void k_convw(const float* __restrict__ src, u16* __restrict__ dst,
                        int n, int rshift) {
    int i = blockIdx.x * 256 + threadIdx.x;
    if (i < n) {
        int gate = (i >> rshift) >> 8;
        float s = (gate == 2) ? TWO_L2E : L2E;
        dst[i] = f2bf(src[i] * s);
    }
}
__global__ void k_bias(const float* __restrict__ a, const float* __restrict__ b,
                       float* __restrict__ o, int n) {
    int i = blockIdx.x * 256 + threadIdx.x;
    if (i < n) {
        float s = ((i >> 8) == 2) ? TWO_L2E : L2E;
        o[i] = (a[i] + b[i]) * s;
    }
}
// W_hh [1024][256] -> frag-order Wf[((wave*8+kf)*8+f)*512 + lane*8 + e],
// prescaled by gate (gate = f>>1).
__global__ void k_wshuf(const u16* __restrict__ src, u16* __restrict__ dst) {
    int idx = blockIdx.x;                 // 512 blocks = (wave*8+kf)*8+f
    int f = idx & 7, kf = (idx >> 3) & 7, wave = idx >> 6;
    int lane = threadIdx.x;               // 64 threads
    int ml = lane & 15, q = lane >> 4;
    int row = (f >> 1) * 256 + wave * 32 + (f & 1) * 16 + ml;
    int col = kf * 32 + q * 8;
    float s = ((f >> 1) == 2) ? TWO_L2E : L2E;
    const u16* sp = &src[(size_t)row * 256 + col];
    u16* dp = &dst[(size_t)idx * 512 + lane * 8];
    #pragma unroll
    for (int e = 0; e < 8; ++e)
        dp[e] = f2bf(bf2f(sp[e]) * s);
}

// ---------------- mega: rec (32 blocks) + gemmA (256) + gemmB (256) --------
__global__ __attribute__((amdgpu_flat_work_group_size(512, 512),
                          amdgpu_waves_per_eu(2, 2))) void mega(
    const float* __restrict__ x,
    const u16* __restrict__ Wih0b, const u16* __restrict__ Whh0f,
    const u16* __restrict__ Wih1b, const u16* __restrict__ Whh1f,
    const float* __restrict__ bias0, const float* __restrict__ bias1,
    u16* __restrict__ xp0base, u16* __restrict__ xp1base,
    u16* __restrict__ h0cbase, float* __restrict__ hlast,
    u16* __restrict__ hs0, float* __restrict__ cs0,
    u16* __restrict__ hs1, float* __restrict__ cs1, int d)
{
    __shared__ __align__(16) u16 SMEM[73984];   // 147968 B, overlaid per role
    const int tid = threadIdx.x;

    if (blockIdx.x < 32) {
        // =================== rec ===================
        const int L   = blockIdx.x >> 4;
        const int blk = blockIdx.x & 15;
        const int chunk = L ? d - 3 : d - 1;
        if (chunk < 0 || chunk >= NCH) return;
        const u16* xp = (L ? xp1base : xp0base) + (size_t)(chunk & 1) * XPCH;
        const u16* Wf = L ? Whh1f : Whh0f;
        u16*  hs = L ? hs1 : hs0;
        float* cs = L ? cs1 : cs0;
        u16* h0c = h0cbase + (size_t)(chunk & 1) * H0CCH;
        const int init = (chunk == 0);

        u16* WL = SMEM;                                   // 131072 B
        u16 (*hAp)[264] = (u16 (*)[264])(SMEM + 65536);   // [2*16][264]

        const int wave = tid >> 6, lane = tid & 63;
        const int ml   = lane & 15, q = lane >> 4;
        const int ub   = wave * 32;
        const int bb0  = blk * 16;

        // frag-order W base for this wave/lane: all accesses lane-contiguous
        const u16* wfb = Wf + (size_t)wave * 32768 + lane * 8;

        // stage W k-frags 0-1 into LDS (contiguous 1KB per wave inst)
        const int wlb = (wave * 1024 + lane) * 8;
        #pragma unroll
        for (int kf = 0; kf < 2; ++kf)
            #pragma unroll
            for (int f = 0; f < 8; ++f)
                *(bf16x8*)&WL[wlb + (kf * 8 + f) * 512] =
                    *(const bf16x8*)(wfb + (kf * 8 + f) * 512);

        // W k-frags 2-5 persistent in registers
        bf16x8 wreg[4][8];
        #pragma unroll
        for (int kf = 2; kf < 6; ++kf)
            #pragma unroll
            for (int f = 0; f < 8; ++f)
                wreg[kf - 2][f] = *(const bf16x8*)(wfb + (kf * 8 + f) * 512);

        // c kept in 2log2e-scaled domain inside the loop
        float c_[8];
        if (init) {
            for (int i = tid; i < 16 * 264; i += 512) ((u16*)hAp)[i] = 0;
            #pragma unroll
            for (int i = 0; i < 8; ++i) c_[i] = 0.f;
        } else {
            int m = tid >> 5, j0 = (tid & 31) * 8;
            *(bf16x8*)&hAp[m][j0] = *(const bf16x8*)&hs[(size_t)(bb0 + m) * 256 + j0];
            #pragma unroll
            for (int s = 0; s < 2; ++s)
                #pragma unroll
                for (int r = 0; r < 4; ++r)
                    c_[s * 4 + r] = cs[(size_t)(bb0 + q * 4 + r) * 256 + ub + s * 16 + ml]
                                    * TWO_L2E;
        }

        // xp: [t16+blk][gi][tid][8] -> per-gi contiguous 1KB per wave inst
        const u16* xpt = xp + (size_t)blk * 16384 + (size_t)tid * 8;
        const int m_st = tid >> 5;
        const int j_st = (tid & 31) * 8;

        __syncthreads();

        // software-pipeline prologue: xv(0) and wstr prefetched before loop
        bf16x8 xv[4];
        #pragma unroll
        for (int gi = 0; gi < 4; ++gi)
            xv[gi] = *(const bf16x8*)(xpt + gi * 4096);
        bf16x8 wstr[2][8];
        #pragma unroll
        for (int kf = 0; kf < 2; ++kf)
            #pragma unroll
            for (int f = 0; f < 8; ++f)
                wstr[kf][f] = *(const bf16x8*)(wfb + ((6 + kf) * 8 + f) * 512);

        for (int t = 0; t < TCH; ++t) {
            const int br = t & 1, bw = br ^ 1;

            // acc starts at the xp contribution (MFMA C-in accumulates):
            // acc[gi][s][r] <- xv[gi] element s*4+r. Kills 32 post-adds.
            f32x4 acc[4][2];
            #pragma unroll
            for (int gi = 0; gi < 4; ++gi) {
                const unsigned* xd = (const unsigned*)&xv[gi];
                #pragma unroll
                for (int s = 0; s < 2; ++s) {
                    float l0, h0, l1, h1;
                    unp(xd[s * 2],     l0, h0);
                    unp(xd[s * 2 + 1], l1, h1);
                    acc[gi][s][0] = l0; acc[gi][s][1] = h0;
                    acc[gi][s][2] = l1; acc[gi][s][3] = h1;
                }
            }

            #pragma unroll
            for (int kf = 0; kf < 2; ++kf) {
                bf16x8 a = *(const bf16x8*)&hAp[br * 16 + ml][kf * 32 + q * 8];
                #pragma unroll
                for (int f = 0; f < 8; ++f) {
                    bf16x8 b = *(const bf16x8*)&WL[wlb + (kf * 8 + f) * 512];
                    acc[f >> 1][f & 1] = __builtin_amdgcn_mfma_f32_16x16x32_bf16(
                        a, b, acc[f >> 1][f & 1], 0, 0, 0);
                }
            }
            #pragma unroll
            for (int kf = 2; kf < 6; ++kf) {
                bf16x8 a = *(const bf16x8*)&hAp[br * 16 + ml][kf * 32 + q * 8];
                #pragma unroll
                for (int f = 0; f < 8; ++f)
                    acc[f >> 1][f & 1] = __builtin_amdgcn_mfma_f32_16x16x32_bf16(
                        a, wreg[kf - 2][f], acc[f >> 1][f & 1], 0, 0, 0);
            }
            // kf6-7: wstr was prefetched a full step ago -> no VMEM stall here
            #pragma unroll
            for (int kf = 6; kf < 8; ++kf) {
                bf16x8 a = *(const bf16x8*)&hAp[br * 16 + ml][kf * 32 + q * 8];
                #pragma unroll
                for (int f = 0; f < 8; ++f)
                    acc[f >> 1][f & 1] = __builtin_amdgcn_mfma_f32_16x16x32_bf16(
                        a, wstr[kf - 6][f], acc[f >> 1][f & 1], 0, 0, 0);
            }
            // reload wstr for t+1 (WAR orders issue here; drains under step)
            #pragma unroll
            for (int kf = 0; kf < 2; ++kf)
                #pragma unroll
                for (int f = 0; f < 8; ++f)
                    wstr[kf][f] = *(const bf16x8*)(wfb + ((6 + kf) * 8 + f) * 512);

            // activations + cell update. Pre-activations prescaled by log2e
            // (2log2e for g) -> raw exp2. c in 2log2e domain: gg' = 2L2E*tanh
            // (same fma, new constants), cc' = fg*c' + ig*gg',
            // tanh(cc) = 1 - 2*rcp(1+ex2(cc')) -- no mul on the chain.
            #pragma unroll
            for (int s = 0; s < 2; ++s) {
                const int j = ub + s * 16 + ml;
                float hv[4];
                #pragma unroll
                for (int r = 0; r < 4; ++r) {
                    float ig = __builtin_amdgcn_rcpf(1.f + ex2(-acc[0][s][r]));
                    float fg = __builtin_amdgcn_rcpf(1.f + ex2(-acc[1][s][r]));
                    float gg2 = TWO_L2E - FOUR_L2E *
                        __builtin_amdgcn_rcpf(1.f + ex2(acc[2][s][r]));
                    float og = __builtin_amdgcn_rcpf(1.f + ex2(-acc[3][s][r]));
                    float cc2 = fg * c_[s * 4 + r] + ig * gg2;
                    c_[s * 4 + r] = cc2;
                    hv[r] = og * (1.f - 2.f *
                        __builtin_amdgcn_rcpf(1.f + ex2(cc2)));
                }
                unsigned p01, p23;
                asm("v_cvt_pk_bf16_f32 %0, %1, %2" : "=v"(p01) : "v"(hv[0]), "v"(hv[1]));
                asm("v_cvt_pk_bf16_f32 %0, %1, %2" : "=v"(p23) : "v"(hv[2]), "v"(hv[3]));
                hAp[bw * 16 + q * 4 + 0][j] = (u16)p01;
                hAp[bw * 16 + q * 4 + 1][j] = (u16)(p01 >> 16);
                hAp[bw * 16 + q * 4 + 2][j] = (u16)p23;
                hAp[bw * 16 + q * 4 + 3][j] = (u16)(p23 >> 16);
                if (L == 1 && chunk == NCH - 1 && t == TCH - 1) {
                    #pragma unroll
                    for (int r = 0; r < 4; ++r)
                        hlast[(size_t)(bb0 + q * 4 + r) * 256 + j] = hv[r];
                }
            }
            // reload xv for t+1 (last step reads past chunk -- mapped, unused)
            xpt += XPSTEP;
            #pragma unroll
            for (int gi = 0; gi < 4; ++gi)
                xv[gi] = *(const bf16x8*)(xpt + gi * 4096);

            // publish h(t+1): only hA ds_writes gate the barrier
            asm volatile("s_waitcnt lgkmcnt(0)\n\ts_barrier" ::: "memory");

            if (L == 0)
                *(bf16x8*)&h0c[((size_t)t * 256 + bb0 + m_st) * 256 + j_st] =
                    *(const bf16x8*)&hAp[bw * 16 + m_st][j_st];
        }

        // persist state (TCH even -> final h is in buf 0); c back to plain domain
        #pragma unroll
        for (int s = 0; s < 2; ++s)
            #pragma unroll
            for (int r = 0; r < 4; ++r)
                cs[(size_t)(bb0 + q * 4 + r) * 256 + ub + s * 16 + ml] =
                    c_[s * 4 + r] * INV_TWO_L2E;
        {
            int m = tid >> 5, j0 = (tid & 31) * 8;
            *(bf16x8*)&hs[(size_t)(bb0 + m) * 256 + j0] = *(const bf16x8*)&hAp[m][j0];
        }
        return;
    }

    // =================== gemm (A: xp0 from x; B: xp1 from h0c) ===================
    const int role = (blockIdx.x < 288) ? 0 : 1;
    const int bid  = blockIdx.x - (role ? 288 : 32);
    const int chunk = role ? d - 2 : d;
    if (chunk < 0 || chunk >= NCH) return;

    const int K = role ? 256 : 64;
    const u16* Wp = role ? Wih1b : Wih0b;
    const float* bias = role ? bias1 : bias0;
    u16* out = (role ? xp1base : xp0base) + (size_t)(chunk & 1) * XPCH;
    const u16* A1 = h0cbase + (size_t)(chunk & 1) * H0CCH;   // role B source

    u16 (*As)[40] = (u16 (*)[40])SMEM;            // [128][40]
    u16 (*Bs)[40] = (u16 (*)[40])(SMEM + 5120);   // [256][40]

    const int mb = bid >> 2, nb = bid & 3;
    const int n0 = nb * 256;
    const int wave = tid >> 6, lane = tid & 63;
    const int wm = wave >> 2, wn = wave & 3;      // 2 x 4 wave grid -> 128x256 tile
    const int ml = lane & 15, q = lane >> 4;
    const int tloc = mb >> 1;
    const int bbas = (mb & 1) * 128;
    const int tt = role ? tloc : chunk * TCH + tloc;

    f32x4 acc[4][4];
    #pragma unroll
    for (int mi = 0; mi < 4; ++mi)
        #pragma unroll
        for (int ni = 0; ni < 4; ++ni)
            acc[mi][ni] = (f32x4)0.f;

    const int nk = K >> 5;
    for (int kt = 0; kt < nk; ++kt) {
        __syncthreads();
        {
            int row = tid >> 2, kb = tid & 3;
            if (role) {
                *(uint4*)&As[row][kb * 8] = *(const uint4*)(
                    A1 + (size_t)tt * 65536 + (size_t)(bbas + row) * 256 + kt * 32 + kb * 8);
            } else {
                const float* xs = x + (size_t)(bbas + row) * 32768 + (size_t)tt * 64
                                    + kt * 32 + kb * 8;
                float4 fa = *(const float4*)xs;
                float4 fb = *(const float4*)(xs + 4);
                uint4 v;
                v.x = f2bf(fa.x) | ((unsigned)f2bf(fa.y) << 16);
                v.y = f2bf(fa.z) | ((unsigned)f2bf(fa.w) << 16);
                v.z = f2bf(fb.x) | ((unsigned)f2bf(fb.y) << 16);
                v.w = f2bf(fb.z) | ((unsigned)f2bf(fb.w) << 16);
                *(uint4*)&As[row][kb * 8] = v;
            }
            #pragma unroll
            for (int i = 0; i < 2; ++i) {
                int c2 = tid + i * 512, r2 = c2 >> 2, k2 = c2 & 3;
                *(uint4*)&Bs[r2][k2 * 8] = *(const uint4*)(
                    Wp + (size_t)(n0 + r2) * K + kt * 32 + k2 * 8);
            }
        }
        __syncthreads();
        bf16x8 af[4], bfr[4];
        #pragma unroll
        for (int mi = 0; mi < 4; ++mi)
            af[mi] = *(const bf16x8*)&As[wm * 64 + mi * 16 + ml][q * 8];
        #pragma unroll
        for (int ni = 0; ni < 4; ++ni)
            bfr[ni] = *(const bf16x8*)&Bs[wn * 64 + ni * 16 + ml][q * 8];
        #pragma unroll
        for (int mi = 0; mi < 4; ++mi)
            #pragma unroll
            for (int ni = 0; ni < 4; ++ni)
                acc[mi][ni] = __builtin_amdgcn_mfma_f32_16x16x32_bf16(
                    af[mi], bfr[ni], acc[mi][ni], 0, 0, 0);
    }

    // epilogue -> xp (R11 layout, VERIFIED form):
    // el = ((tloc*16+blk2)*4+gi)*512*8 ... = ((x)*512 + tid_r)*8 + s*4 + rr
    #pragma unroll
    for (int ni = 0; ni < 4; ++ni) {
        int gc = n0 + wn * 64 + ni * 16 + ml;
        int gi = gc >> 8, u = gc & 255;
        int wv = u >> 5, s = (u >> 4) & 1, mlr = u & 15;
        float bv = bias[gc];
        #pragma unroll
        for (int mi = 0; mi < 4; ++mi) {
            int rowbase = bbas + wm * 64 + mi * 16;        // multiple of 16
            int blk2 = rowbase >> 4;
            size_t el0 = ((size_t)((tloc * 16 + blk2) * 4 + gi) * 512
                          + wv * 64 + q * 16 + mlr) * 8 + s * 4;
            #pragma unroll
            for (int rr = 0; rr < 4; ++rr)
                out[el0 + rr] = f2bf(acc[mi][ni][rr] + bv);
        }
    }
}

// ---------------- FC head ----------------
__global__ void fc_k(const float* __restrict__ h, const float* __restrict__ w,
                     const float* __restrict__ b, float* __restrict__ out)
{
    int bb = blockIdx.x, lane = threadIdx.x;
    float s = 0.f;
    for (int j = lane; j < 256; j += 64) s += h[bb * 256 + j] * w[j];
    #pragma unroll
    for (int off = 32; off > 0; off >>= 1) s += __shfl_down(s, off);
    if (lane == 0) out[bb] = s + b[0];
}

extern "C" void kernel_launch(void* const* d_in, const int* in_sizes, int n_in,
                              void* d_out, int out_size, void* d_ws, size_t ws_size,
                              hipStream_t stream)
{
    const float* x    = (const float*)d_in[0];
    const float* Wih0 = (const float*)d_in[1];
    const float* Whh0 = (const float*)d_in[2];
    const float* bih0 = (const float*)d_in[3];
    const float* bhh0 = (const float*)d_in[4];
    const float* Wih1 = (const float*)d_in[5];
    const float* Whh1 = (const float*)d_in[6];
    const float* bih1 = (const float*)d_in[7];
    const float* bhh1 = (const float*)d_in[8];
    const float* fcw  = (const float*)d_in[9];
    const float* fcb  = (const float*)d_in[10];
    float* out = (float*)d_out;

    // workspace layout, total ~75.6 MB
    char* ws = (char*)d_ws;
    u16*   xp0b  = (u16*)(ws);                  // 33554432  (2 chunks)
    u16*   xp1b  = (u16*)(ws + 33554432);       // 33554432  (2 chunks)
    u16*   h0cb  = (u16*)(ws + 67108864);       //  8388608  (2 chunks)
    u16*   Wih0b = (u16*)(ws + 75497472);       //   131072
    u16*   Whh0b = (u16*)(ws + 75628544);       //   524288
    u16*   Wih1b = (u16*)(ws + 76152832);       //   524288
    u16*   Whh1b = (u16*)(ws + 76677120);       //   524288
    float* bias0 = (float*)(ws + 77201408);     //     4096
    float* bias1 = (float*)(ws + 77205504);     //     4096
    u16*   hs0   = (u16*)(ws + 77209600);       //   131072
    float* cs0   = (float*)(ws + 77340672);     //   262144
    u16*   hs1   = (u16*)(ws + 77602816);       //   131072
    float* cs1   = (float*)(ws + 77733888);     //   262144
    float* h1l   = (float*)(ws + 77996032);     //   262144
    u16*   Whh0f = (u16*)(ws + 78258176);       //   524288  frag-order W (scaled)
    u16*   Whh1f = (u16*)(ws + 78782464);       //   524288

    k_convw<<<256,  256, 0, stream>>>(Wih0, Wih0b, 65536, 6);    // K=64
    k_conv<<<1024, 256, 0, stream>>>(Whh0, Whh0b, 262144);
    k_convw<<<1024, 256, 0, stream>>>(Wih1, Wih1b, 262144, 8);   // K=256
    k_conv<<<1024, 256, 0, stream>>>(Whh1, Whh1b, 262144);
    k_bias<<<4, 256, 0, stream>>>(bih0, bhh0, bias0, 1024);
    k_bias<<<4, 256, 0, stream>>>(bih1, bhh1, bias1, 1024);
    k_wshuf<<<512, 64, 0, stream>>>(Whh0b, Whh0f);
    k_wshuf<<<512, 64, 0, stream>>>(Whh1b, Whh1f);

    for (int d = 0; d <= NCH + 2; ++d)   // d = 0..18
        mega<<<544, 512, 0, stream>>>(x, Wih0b, Whh0f, Wih1b, Whh1f,
                                      bias0, bias1, xp0b, xp1b, h0cb, h1l,
                                      hs0, cs0, hs1, cs1, d);
    fc_k<<<256, 64, 0, stream>>>(h1l, fcw, fcb, out);
}